// Round 6
// baseline (448.817 us; speedup 1.0000x reference)
//
#include <hip/hip_runtime.h>
#include <math.h>

#define WAVE 64
#define NC 21

__device__ __forceinline__ unsigned f32_ord(float f) {
    unsigned u = __float_as_uint(f);
    return (u & 0x80000000u) ? ~u : (u | 0x80000000u);
}

__device__ __forceinline__ unsigned wave_min_u32(unsigned v) {
#pragma unroll
    for (int off = 32; off >= 1; off >>= 1) {
        unsigned o = (unsigned)__shfl_xor((int)v, off, WAVE);
        v = (o < v) ? o : v;
    }
    return v;
}

__device__ __forceinline__ float wave_max_f32(float v) {
#pragma unroll
    for (int off = 32; off >= 1; off >>= 1)
        v = fmaxf(v, __shfl_xor(v, off, WAVE));
    return v;
}

__device__ __forceinline__ float wave_sum_f32(float v) {
#pragma unroll
    for (int off = 32; off >= 1; off >>= 1)
        v += __shfl_xor(v, off, WAVE);
    return v;
}

struct SelShm {
    int hist[4][256];   // per-wave histograms
    int sel[64];
    int swave[4];
    int scnt;
};

// All-waves-redundant scan of the 4x256 histograms: finds digit T such that
// cumulative count crosses `need`; updates need (-= count below T) and
// Vhi = (Vhi<<8)|T. Every thread computes the identical (uniform) result.
__device__ __forceinline__ void radix_scan_step(SelShm& shm, int lane,
                                                int& need, unsigned& Vhi) {
    int i0 = 4 * lane;
    int b0 = shm.hist[0][i0]   + shm.hist[1][i0]   + shm.hist[2][i0]   + shm.hist[3][i0];
    int b1 = shm.hist[0][i0+1] + shm.hist[1][i0+1] + shm.hist[2][i0+1] + shm.hist[3][i0+1];
    int b2 = shm.hist[0][i0+2] + shm.hist[1][i0+2] + shm.hist[2][i0+2] + shm.hist[3][i0+2];
    int b3 = shm.hist[0][i0+3] + shm.hist[1][i0+3] + shm.hist[2][i0+3] + shm.hist[3][i0+3];
    int lsum = b0 + b1 + b2 + b3;
    int c = lsum;                       // inclusive scan over lanes
#pragma unroll
    for (int off = 1; off < 64; off <<= 1) {
        int o = __shfl_up(c, off, WAVE);
        c += (lane >= off) ? o : 0;
    }
    unsigned long long mball = __ballot(c >= need);
    int Ls = __ffsll((unsigned long long)mball) - 1;   // first crossing lane
    int cL = __shfl(c, Ls, WAVE);
    int lsumL = __shfl(lsum, Ls, WAVE);
    int B0 = __shfl(b0, Ls, WAVE);
    int B1 = __shfl(b1, Ls, WAVE);
    int B2 = __shfl(b2, Ls, WAVE);
    int e = cL - lsumL;                 // exclusive count before lane Ls' bins
    int T;
    if (e + B0 >= need)                { T = 4 * Ls + 0; }
    else if (e + B0 + B1 >= need)      { T = 4 * Ls + 1; e += B0; }
    else if (e + B0 + B1 + B2 >= need) { T = 4 * Ls + 2; e += B0 + B1; }
    else                               { T = 4 * Ls + 3; e += B0 + B1 + B2; }
    need -= e;
    Vhi = (Vhi << 8) | (unsigned)T;
}

// ---------------------------------------------------------------------------
// Block-wide exact top-NS set selection via 4-pass radix select.
// 256 threads; thread t owns keys g = j*256+t. Result: shm.sel[0..NS) holds
// the NS selected global indices (arbitrary order). Tie-break identical to
// jax.lax.top_k (lower global index first).
// ---------------------------------------------------------------------------
template <int NI, int NS>
__device__ __forceinline__ void block_select_topNS(
    const float* __restrict__ rp,   // [NI,3] coords for this batch
    float qx, float qy, float qz, float nq,
    SelShm& shm, int tid)
{
    constexpr int NPL = (NI + 255) / 256;
    constexpr bool FULL = (NPL * 256 == NI);
    const int lane = tid & 63;
    const int wid = tid >> 6;
    const unsigned long long lmask = (1ull << lane) - 1ull;

    unsigned ok[NPL];
#pragma unroll
    for (int j = 0; j < NPL; ++j) {
        int g = j * 256 + tid;
        unsigned o = 0xFFFFFFFFu;
        if (FULL || g < NI) {
            float rx = rp[3*g], ry = rp[3*g+1], rz = rp[3*g+2];
            float nr = rx*rx + ry*ry + rz*rz;
            float dot = qx*rx + qy*ry + qz*rz;
            o = f32_ord(-2.0f*dot + nq + nr);   // identical expr to R1-R5
        }
        ok[j] = o;
    }

    // clear histograms + scnt
    int* hf = &shm.hist[0][0];
#pragma unroll
    for (int i = 0; i < 4; ++i) hf[i * 256 + tid] = 0;
    if (tid == 0) shm.scnt = 0;
    __syncthreads();

    int need = NS;
    unsigned Vhi = 0;

    // pass 0: digit = bits[31:24], all keys active
#pragma unroll
    for (int j = 0; j < NPL; ++j)
        atomicAdd(&shm.hist[wid][ok[j] >> 24], 1);
    __syncthreads();
    radix_scan_step(shm, lane, need, Vhi);
    __syncthreads();                        // hist reads done
#pragma unroll
    for (int i = 0; i < 4; ++i) hf[i * 256 + tid] = 0;
    __syncthreads();

    // passes 1..3
#pragma unroll
    for (int pass = 1; pass < 4; ++pass) {
        const int shift = 24 - 8 * pass;    // 16, 8, 0
#pragma unroll
        for (int j = 0; j < NPL; ++j) {
            if ((ok[j] >> (shift + 8)) == Vhi)
                atomicAdd(&shm.hist[wid][(ok[j] >> shift) & 255], 1);
        }
        __syncthreads();
        radix_scan_step(shm, lane, need, Vhi);
        __syncthreads();
        if (pass < 3) {
#pragma unroll
            for (int i = 0; i < 4; ++i) hf[i * 256 + tid] = 0;
            __syncthreads();
        }
    }

    const unsigned V = Vhi;                 // exact NS-th smallest key
    const int R = need;                     // ties at V to take (>= 1)
    const int clt = NS - R;                 // count of keys < V

    // compact keys < V (order in sel[] arbitrary — set semantics)
#pragma unroll
    for (int j = 0; j < NPL; ++j) {
        bool s = ok[j] < V;
        unsigned long long mk = __ballot(s);
        int n = __popcll(mk);
        if (n) {                            // wave-uniform
            int wb = 0;
            if (lane == 0) wb = atomicAdd(&shm.scnt, n);
            wb = __shfl(wb, 0, WAVE);
            if (s) shm.sel[wb + __popcll(mk & lmask)] = j * 256 + tid;
        }
    }

    // ties at V: take R smallest global indices among ok[j] == V
    unsigned consumed = 0u;                 // NPL <= 16
    for (int r = 0; r < R; ++r) {
        int bj = -1;
#pragma unroll
        for (int j = NPL - 1; j >= 0; --j)
            if (ok[j] == V && !((consumed >> j) & 1u)) bj = j;
        unsigned g = (bj >= 0) ? (unsigned)(bj * 256 + tid) : 0xFFFFFFFFu;
        unsigned mg = wave_min_u32(g);
        if (lane == 0) shm.swave[wid] = (int)mg;
        __syncthreads();
        unsigned t0 = (unsigned)shm.swave[0], t1 = (unsigned)shm.swave[1];
        unsigned t2 = (unsigned)shm.swave[2], t3 = (unsigned)shm.swave[3];
        unsigned ta = (t0 < t1) ? t0 : t1;
        unsigned tb = (t2 < t3) ? t2 : t3;
        unsigned t = (ta < tb) ? ta : tb;
        if (bj >= 0 && g == t) consumed |= (1u << bj);
        if (tid == 0) shm.sel[clt + r] = (int)t;
        __syncthreads();                    // sel fully visible after last iter
    }
}

// ---------------------------------------------------------------------------
template <int NQ, int K>
__device__ __forceinline__ void knn_level(
    const float* __restrict__ qc, const float* __restrict__ rc,
    const int* __restrict__ rl, int* __restrict__ out,
    int qb, SelShm& shm, int tid)
{
    int b = qb / NQ, qi = qb - b * NQ;
    const float* qp = qc + ((long)b * NQ + qi) * 3;
    float qx = qp[0], qy = qp[1], qz = qp[2];
    float nq = qx*qx + qy*qy + qz*qz;
    block_select_topNS<4096, K>(rc + (long)b * 4096 * 3, qx, qy, qz, nq, shm, tid);
    if ((tid >> 6) == 0) {
        int lane = tid & 63;
        int lb = (lane < K) ? rl[(long)b * 4096 + shm.sel[lane]] : -1;
        int cnt = 0;
#pragma unroll
        for (int k = 0; k < K; ++k) {
            int lk = __shfl(lb, k, WAVE);
            cnt += (lk == lane) ? 1 : 0;
        }
        int key = (lane < NC) ? ((cnt << 8) | (255 - lane)) : 0;
#pragma unroll
        for (int off = 32; off >= 1; off >>= 1) {
            int o = __shfl_xor(key, off, WAVE);
            key = (o > key) ? o : key;
        }
        if (lane == 0) out[(long)b * NQ + qi] = 255 - (key & 255);
    }
}

template <int NI, int NS>
__device__ __forceinline__ void boundary_level(
    const float* __restrict__ coord, const float* __restrict__ feat,
    const int* __restrict__ lbl,
    double* __restrict__ pos, double* __restrict__ neg, int* __restrict__ anyf,
    int qb, SelShm& shm, int tid)
{
    int b = qb / NI, qi = qb - b * NI;
    const float* qp = coord + ((long)b * NI + qi) * 3;
    float qx = qp[0], qy = qp[1], qz = qp[2];
    float nq = qx*qx + qy*qy + qz*qz;
    block_select_topNS<NI, NS>(coord + (long)b * NI * 3, qx, qy, qz, nq, shm, tid);
    if ((tid >> 6) == 0) {
        int lane = tid & 63;
        int center = lbl[(long)b * NI + qi];
        bool m = false;
        float dj = -INFINITY;
        if (lane < NS) {
            int nb = shm.sel[lane];
            m = (lbl[(long)b * NI + nb] == center);
            const float4* fq = (const float4*)(feat + ((long)b * NI + qi) * 32);
            const float4* fn = (const float4*)(feat + ((long)b * NI + nb) * 32);
            float s = 0.f;
#pragma unroll
            for (int d = 0; d < 8; ++d) {
                float4 a = fq[d], c = fn[d];
                float d0 = a.x - c.x, d1 = a.y - c.y;
                float d2 = a.z - c.z, d3 = a.w - c.w;
                s += d0*d0 + d1*d1 + d2*d2 + d3*d3;
            }
            dj = -sqrtf(s + 1e-6f);
        }
        unsigned long long mb = __ballot(m);
        int cnt = __popcll(mb);
        float mxv = wave_max_f32(dj);          // lanes >= NS hold -inf
        float ej = 0.f, pj = 0.f;
        if (lane < NS) {
            ej = expf(dj - mxv);               // TEMPERATURE == 1
            pj = m ? ej : 0.f;
        }
        float se = wave_sum_f32(ej);
        float sp = wave_sum_f32(pj);
        bool pm = (cnt > 0) && (cnt < NS);
        if (pm && lane == 0) {
            atomicAdd(pos, (double)sp);
            atomicAdd(neg, (double)se);
            *anyf = 1;
        }
    }
}

// ---------------------------------------------------------------------------
__global__ __launch_bounds__(256) void knn_fused(
    const float* __restrict__ c1, const float* __restrict__ c2,
    const float* __restrict__ c3, const float* __restrict__ c4,
    const float* __restrict__ c0, const int* __restrict__ labels,
    int* __restrict__ lbl1, int* __restrict__ lbl2,
    int* __restrict__ lbl3, int* __restrict__ lbl4,
    double* __restrict__ posA, double* __restrict__ negA,
    int* __restrict__ anyA, int B)
{
    __shared__ SelShm shm;
    int blk = blockIdx.x, tid = threadIdx.x;
    int n1 = B * 1024, n2 = n1 + B * 256, n3 = n2 + B * 64, n4 = n3 + B * 16;
    if (blk < n1)      knn_level<1024, 4>(c1, c0, labels, lbl1, blk,      shm, tid);
    else if (blk < n2) knn_level<256,  8>(c2, c0, labels, lbl2, blk - n1, shm, tid);
    else if (blk < n3) knn_level<64,  12>(c3, c0, labels, lbl3, blk - n2, shm, tid);
    else if (blk < n4) knn_level<16,  16>(c4, c0, labels, lbl4, blk - n3, shm, tid);
    else if (tid < 5) { posA[tid] = 0.0; negA[tid] = 0.0; anyA[tid] = 0; }
}

__global__ __launch_bounds__(256) void boundary_fused(
    const float* __restrict__ c0, const float* __restrict__ c1,
    const float* __restrict__ c2, const float* __restrict__ c3,
    const float* __restrict__ c4,
    const float* __restrict__ f0, const float* __restrict__ f1,
    const float* __restrict__ f2, const float* __restrict__ f3,
    const float* __restrict__ f4,
    const int* __restrict__ labels, const int* __restrict__ lbl1,
    const int* __restrict__ lbl2, const int* __restrict__ lbl3,
    const int* __restrict__ lbl4,
    double* __restrict__ posA, double* __restrict__ negA,
    int* __restrict__ anyA, int B)
{
    __shared__ SelShm shm;
    int blk = blockIdx.x, tid = threadIdx.x;
    int m0 = B * 4096, m1 = m0 + B * 1024, m2 = m1 + B * 256;
    int m3 = m2 + B * 64, m4 = m3 + B * 16;
    if (blk < m0)
        boundary_level<4096, 64>(c0, f0, labels, posA+0, negA+0, anyA+0, blk,      shm, tid);
    else if (blk < m1)
        boundary_level<1024, 32>(c1, f1, lbl1,   posA+1, negA+1, anyA+1, blk - m0, shm, tid);
    else if (blk < m2)
        boundary_level<256,  16>(c2, f2, lbl2,   posA+2, negA+2, anyA+2, blk - m1, shm, tid);
    else if (blk < m3)
        boundary_level<64,    8>(c3, f3, lbl3,   posA+3, negA+3, anyA+3, blk - m2, shm, tid);
    else if (blk < m4)
        boundary_level<16,    4>(c4, f4, lbl4,   posA+4, negA+4, anyA+4, blk - m3, shm, tid);
}

__global__ void finalize_kernel(const double* __restrict__ pos,
                                const double* __restrict__ neg,
                                const int* __restrict__ anyf,
                                float* __restrict__ out) {
    if (threadIdx.x == 0 && blockIdx.x == 0) {
        float loss = 0.f;
        for (int i = 0; i < 5; ++i) {
            if (anyf[i]) {
                float p = (float)pos[i];
                float n = (float)neg[i];
                loss += -logf(p / (n + 1e-6f));
            }
        }
        out[0] = loss;
    }
}

extern "C" void kernel_launch(void* const* d_in, const int* in_sizes, int n_in,
                              void* d_out, int out_size, void* d_ws, size_t ws_size,
                              hipStream_t stream) {
    (void)out_size; (void)ws_size;
    const int* labels = (const int*)d_in[0];
    const float* coord[5];
    const float* feat[5];
    bool interleaved = (n_in >= 3 && in_sizes[2] == 2 * 4096 * 32);
    if (interleaved) {
        for (int i = 0; i < 5; ++i) {
            coord[i] = (const float*)d_in[1 + 2 * i];
            feat[i]  = (const float*)d_in[2 + 2 * i];
        }
    } else {
        for (int i = 0; i < 5; ++i) {
            coord[i] = (const float*)d_in[1 + i];
            feat[i]  = (const float*)d_in[6 + i];
        }
    }
    int B = in_sizes[0] / 4096;   // = 2

    double* posA = (double*)d_ws;            // 5 doubles
    double* negA = posA + 5;                 // 5 doubles
    int* anyA = (int*)(negA + 5);            // 5 ints (+3 pad)
    int* lbl1 = anyA + 8;
    int* lbl2 = lbl1 + B * 1024;
    int* lbl3 = lbl2 + B * 256;
    int* lbl4 = lbl3 + B * 64;

    int knn_grid = B * (1024 + 256 + 64 + 16) + 1;     // +1 block does init
    hipLaunchKernelGGL(knn_fused, dim3(knn_grid), dim3(256), 0, stream,
                       coord[1], coord[2], coord[3], coord[4],
                       coord[0], labels, lbl1, lbl2, lbl3, lbl4,
                       posA, negA, anyA, B);

    int bnd_grid = B * (4096 + 1024 + 256 + 64 + 16);
    hipLaunchKernelGGL(boundary_fused, dim3(bnd_grid), dim3(256), 0, stream,
                       coord[0], coord[1], coord[2], coord[3], coord[4],
                       feat[0], feat[1], feat[2], feat[3], feat[4],
                       labels, lbl1, lbl2, lbl3, lbl4,
                       posA, negA, anyA, B);

    hipLaunchKernelGGL(finalize_kernel, dim3(1), dim3(1), 0, stream,
                       posA, negA, anyA, (float*)d_out);
}